// Round 1
// baseline (497.006 us; speedup 1.0000x reference)
//
#include <hip/hip_runtime.h>
#include <math.h>

#define NDIN 128
#define NHID 128
#define NDOUT 64

__device__ __forceinline__ float gelu_exact(float x) {
    return 0.5f * x * (1.0f + erff(x * 0.70710678118654752f));
}

// ---------------- preprocessing ----------------

__global__ void count_kernel(const int* __restrict__ dst, int* __restrict__ count, int E) {
    int e = blockIdx.x * blockDim.x + threadIdx.x;
    if (e < E) atomicAdd(&count[dst[e]], 1);
}

// single-block exclusive scan over count -> rowptr[0..n], rowptr[n] = total
__global__ void scan_kernel(const int* __restrict__ count, int* __restrict__ rowptr, int n) {
    __shared__ int sums[1024];
    int t = threadIdx.x;
    int chunk = (n + 1023) / 1024;
    int start = t * chunk;
    int end = start + chunk; if (end > n) end = n;
    int s = 0;
    for (int i = start; i < end; i++) s += count[i];
    sums[t] = s;
    __syncthreads();
    for (int off = 1; off < 1024; off <<= 1) {
        int v = (t >= off) ? sums[t - off] : 0;
        __syncthreads();
        sums[t] += v;
        __syncthreads();
    }
    int pre = (t == 0) ? 0 : sums[t - 1];
    for (int i = start; i < end; i++) { rowptr[i] = pre; pre += count[i]; }
    if (t == 1023) rowptr[n] = sums[1023];
}

__global__ void dinv_kernel(const int* __restrict__ count, float* __restrict__ dinv, int n) {
    int i = blockIdx.x * blockDim.x + threadIdx.x;
    if (i < n) dinv[i] = rsqrtf((float)(count[i] + 1));   // +1 self-loop, always > 0
}

__global__ void fill_kernel(const int* __restrict__ src, const int* __restrict__ dst,
                            const float* __restrict__ dinv, const int* __restrict__ rowptr,
                            int* __restrict__ cursor, int* __restrict__ adj_src,
                            float* __restrict__ adj_w, int E) {
    int e = blockIdx.x * blockDim.x + threadIdx.x;
    if (e >= E) return;
    int s = src[e], d = dst[e];
    int p = rowptr[d] + atomicAdd(&cursor[d], 1);
    adj_src[p] = s;
    adj_w[p] = dinv[s] * dinv[d];
}

// ---------------- fp32 tiled GEMM: C[M,Ncols] = A[M,K] @ B[K,Ncols] ----------------
// 64x64 tile, BK=16, 4x4 register tile per thread, 256 threads.

__global__ __launch_bounds__(256) void gemm_kernel(
    const float* __restrict__ A, const float* __restrict__ B,
    float* __restrict__ C, int M, int K, int Ncols) {
    __shared__ float lds_a[16][64];   // [k][m]
    __shared__ float lds_b[16][64];   // [k][n]
    int tid = threadIdx.x;
    int bm = blockIdx.x * 64;
    int bn = blockIdx.y * 64;
    int tx = tid & 15;   // col group
    int ty = tid >> 4;   // row group
    float acc[4][4] = {};
    for (int k0 = 0; k0 < K; k0 += 16) {
        // A tile load: 64 rows x 16 k, float4 along k, transpose into lds_a[k][m]
        {
            int r = tid >> 2;
            int kc = (tid & 3) << 2;
            int grow = bm + r;
            float4 av;
            if (grow < M) av = *(const float4*)(A + (size_t)grow * K + k0 + kc);
            else { av.x = 0.f; av.y = 0.f; av.z = 0.f; av.w = 0.f; }
            lds_a[kc + 0][r] = av.x;
            lds_a[kc + 1][r] = av.y;
            lds_a[kc + 2][r] = av.z;
            lds_a[kc + 3][r] = av.w;
        }
        // B tile load: 16 k x 64 n, float4 along n
        {
            int kk = tid >> 4;
            int nc = (tid & 15) << 2;
            *(float4*)&lds_b[kk][nc] = *(const float4*)(B + (size_t)(k0 + kk) * Ncols + bn + nc);
        }
        __syncthreads();
#pragma unroll
        for (int k = 0; k < 16; k++) {
            float4 a4 = *(const float4*)&lds_a[k][ty << 2];
            float4 b4 = *(const float4*)&lds_b[k][tx << 2];
            float av[4] = {a4.x, a4.y, a4.z, a4.w};
            float bv[4] = {b4.x, b4.y, b4.z, b4.w};
#pragma unroll
            for (int i = 0; i < 4; i++)
#pragma unroll
                for (int j = 0; j < 4; j++)
                    acc[i][j] += av[i] * bv[j];
        }
        __syncthreads();
    }
#pragma unroll
    for (int i = 0; i < 4; i++) {
        int grow = bm + (ty << 2) + i;
        if (grow < M) {
            float4 o;
            o.x = acc[i][0]; o.y = acc[i][1]; o.z = acc[i][2]; o.w = acc[i][3];
            *(float4*)(C + (size_t)grow * Ncols + bn + (tx << 2)) = o;
        }
    }
}

// ---------------- aggregation: out[i] = act( sum_e w_e * t[src_e] + dinv[i]^2 * t[i] + b ) ----
// One wave (64 lanes) per node. F=128: float2 per lane. F=64: float per lane.

template <int F, bool DOGELU>
__global__ __launch_bounds__(256) void agg_kernel(
    const float* __restrict__ t, const int* __restrict__ rowptr,
    const int* __restrict__ adj_src, const float* __restrict__ adj_w,
    const float* __restrict__ dinv, const float* __restrict__ bias,
    float* __restrict__ outp, int n) {
    int node = (int)((blockIdx.x * blockDim.x + threadIdx.x) >> 6);
    int lane = threadIdx.x & 63;
    if (node >= n) return;   // wave-uniform exit

    float wself = dinv[node];
    wself *= wself;
    int beg = rowptr[node];
    int end = rowptr[node + 1];

    if (F == 128) {
        const float2* tr = (const float2*)(t + (size_t)node * 128);
        float2 v = tr[lane];
        float accx = wself * v.x, accy = wself * v.y;
        for (int e0 = beg; e0 < end; e0 += 64) {
            int rem = end - e0;
            int j = 0; float w = 0.f;
            if (lane < rem) { j = adj_src[e0 + lane]; w = adj_w[e0 + lane]; }
            int cnt = rem < 64 ? rem : 64;
            for (int i = 0; i < cnt; i++) {
                int jj = __builtin_amdgcn_readlane(j, i);
                float ww = __int_as_float(__builtin_amdgcn_readlane(__float_as_int(w), i));
                float2 u = ((const float2*)(t + (size_t)jj * 128))[lane];
                accx += ww * u.x;
                accy += ww * u.y;
            }
        }
        float2 b = ((const float2*)bias)[lane];
        accx += b.x; accy += b.y;
        if (DOGELU) { accx = gelu_exact(accx); accy = gelu_exact(accy); }
        float2 o; o.x = accx; o.y = accy;
        ((float2*)(outp + (size_t)node * 128))[lane] = o;
    } else {  // F == 64
        float acc = wself * t[(size_t)node * 64 + lane];
        for (int e0 = beg; e0 < end; e0 += 64) {
            int rem = end - e0;
            int j = 0; float w = 0.f;
            if (lane < rem) { j = adj_src[e0 + lane]; w = adj_w[e0 + lane]; }
            int cnt = rem < 64 ? rem : 64;
            for (int i = 0; i < cnt; i++) {
                int jj = __builtin_amdgcn_readlane(j, i);
                float ww = __int_as_float(__builtin_amdgcn_readlane(__float_as_int(w), i));
                acc += ww * t[(size_t)jj * 64 + lane];
            }
        }
        acc += bias[lane];
        if (DOGELU) acc = gelu_exact(acc);
        outp[(size_t)node * 64 + lane] = acc;
    }
}

// ---------------- launch ----------------

extern "C" void kernel_launch(void* const* d_in, const int* in_sizes, int n_in,
                              void* d_out, int out_size, void* d_ws, size_t ws_size,
                              hipStream_t stream) {
    const float* x  = (const float*)d_in[0];
    const int* edge = (const int*)d_in[1];
    const float* W1 = (const float*)d_in[2];
    const float* b1 = (const float*)d_in[3];
    const float* W2 = (const float*)d_in[4];
    const float* b2 = (const float*)d_in[5];
    const float* W3 = (const float*)d_in[6];
    const float* b3 = (const float*)d_in[7];
    float* out = (float*)d_out;

    const int N = in_sizes[0] / NDIN;       // 50000
    const int E = in_sizes[1] / 2;          // 800000
    const int* src = edge;
    const int* dst = edge + E;

    // workspace carve-out (256B aligned)
    char* p = (char*)d_ws;
    auto alloc = [&](size_t bytes) {
        char* q = p;
        p += (bytes + 255) & ~(size_t)255;
        return q;
    };
    int*   count   = (int*)alloc((size_t)N * 4);
    int*   cursor  = (int*)alloc((size_t)N * 4);
    int*   rowptr  = (int*)alloc((size_t)(N + 1) * 4);
    float* dinv    = (float*)alloc((size_t)N * 4);
    int*   adj_src = (int*)alloc((size_t)E * 4);
    float* adj_w   = (float*)alloc((size_t)E * 4);
    float* tbuf    = (float*)alloc((size_t)N * NHID * 4);
    float* hbuf    = (float*)alloc((size_t)N * NHID * 4);

    hipMemsetAsync(count, 0, (size_t)N * 4, stream);
    hipMemsetAsync(cursor, 0, (size_t)N * 4, stream);

    // graph preprocessing
    count_kernel<<<(E + 255) / 256, 256, 0, stream>>>(dst, count, E);
    scan_kernel<<<1, 1024, 0, stream>>>(count, rowptr, N);
    dinv_kernel<<<(N + 255) / 256, 256, 0, stream>>>(count, dinv, N);
    fill_kernel<<<(E + 255) / 256, 256, 0, stream>>>(src, dst, dinv, rowptr, cursor,
                                                     adj_src, adj_w, E);

    dim3 blk(256);
    dim3 g1((N + 63) / 64, NHID / 64);      // 128-wide GEMMs
    dim3 g3((N + 63) / 64, NDOUT / 64);     // 64-wide GEMM
    int agg_blocks = (N + 3) / 4;           // 4 waves (nodes) per 256-thread block

    // layer 1
    gemm_kernel<<<g1, blk, 0, stream>>>(x, W1, tbuf, N, NDIN, NHID);
    agg_kernel<128, true><<<agg_blocks, blk, 0, stream>>>(tbuf, rowptr, adj_src, adj_w,
                                                          dinv, b1, hbuf, N);
    // layer 2
    gemm_kernel<<<g1, blk, 0, stream>>>(hbuf, W2, tbuf, N, NHID, NHID);
    agg_kernel<128, true><<<agg_blocks, blk, 0, stream>>>(tbuf, rowptr, adj_src, adj_w,
                                                          dinv, b2, hbuf, N);
    // layer 3 (no gelu)
    gemm_kernel<<<g3, blk, 0, stream>>>(hbuf, W3, tbuf, N, NHID, NDOUT);
    agg_kernel<64, false><<<agg_blocks, blk, 0, stream>>>(tbuf, rowptr, adj_src, adj_w,
                                                          dinv, b3, out, N);
}

// Round 2
// 385.047 us; speedup vs baseline: 1.2908x; 1.2908x over previous
//
#include <hip/hip_runtime.h>
#include <math.h>

#define NDIN 128
#define NHID 128
#define NDOUT 64

__device__ __forceinline__ float gelu_exact(float x) {
    return 0.5f * x * (1.0f + erff(x * 0.70710678118654752f));
}

// ---------------- preprocessing ----------------

__global__ void count_kernel(const int* __restrict__ dst, int* __restrict__ count, int E) {
    int e = blockIdx.x * blockDim.x + threadIdx.x;
    if (e < E) atomicAdd(&count[dst[e]], 1);
}

// phase A: per-block (256-elem segment) reduction of count
__global__ __launch_bounds__(256) void reduce_blocks_kernel(
    const int* __restrict__ count, int* __restrict__ blocksum, int n) {
    __shared__ int s[256];
    int i = blockIdx.x * 256 + threadIdx.x;
    s[threadIdx.x] = (i < n) ? count[i] : 0;
    __syncthreads();
    for (int off = 128; off > 0; off >>= 1) {
        if (threadIdx.x < off) s[threadIdx.x] += s[threadIdx.x + off];
        __syncthreads();
    }
    if (threadIdx.x == 0) blocksum[blockIdx.x] = s[0];
}

// phase B: single-block scan over block partial sums (nb <= 256); writes rowptr[n]=total
__global__ __launch_bounds__(256) void scan_partials_kernel(
    const int* __restrict__ blocksum, int* __restrict__ blockoff,
    int* __restrict__ rowptr, int nb, int n) {
    __shared__ int s[256];
    int t = threadIdx.x;
    int v = (t < nb) ? blocksum[t] : 0;
    s[t] = v;
    __syncthreads();
    for (int off = 1; off < 256; off <<= 1) {
        int u = (t >= off) ? s[t - off] : 0;
        __syncthreads();
        s[t] += u;
        __syncthreads();
    }
    if (t < nb) blockoff[t] = s[t] - v;   // exclusive
    if (t == 255) rowptr[n] = s[255];     // grand total
}

// phase C: per-block scan of the 256-elem segment + add block offset; also emits dinv
__global__ __launch_bounds__(256) void scan_blocks_kernel(
    const int* __restrict__ count, const int* __restrict__ blockoff,
    int* __restrict__ rowptr, float* __restrict__ dinv, int n) {
    __shared__ int s[256];
    int i = blockIdx.x * 256 + threadIdx.x;
    int v = (i < n) ? count[i] : 0;
    s[threadIdx.x] = v;
    __syncthreads();
    for (int off = 1; off < 256; off <<= 1) {
        int u = (threadIdx.x >= off) ? s[threadIdx.x - off] : 0;
        __syncthreads();
        s[threadIdx.x] += u;
        __syncthreads();
    }
    if (i < n) {
        rowptr[i] = blockoff[blockIdx.x] + s[threadIdx.x] - v;  // exclusive
        dinv[i] = rsqrtf((float)(v + 1));                       // +1 self-loop
    }
}

// fill CSR; consumes count[] as a countdown cursor (atomicSub)
__global__ void fill_kernel(const int* __restrict__ src, const int* __restrict__ dst,
                            const float* __restrict__ dinv, const int* __restrict__ rowptr,
                            int* __restrict__ count, int* __restrict__ adj_src,
                            float* __restrict__ adj_w, int E) {
    int e = blockIdx.x * blockDim.x + threadIdx.x;
    if (e >= E) return;
    int s = src[e], d = dst[e];
    int slot = atomicSub(&count[d], 1) - 1;   // deg-1 .. 0
    int p = rowptr[d] + slot;
    adj_src[p] = s;
    adj_w[p] = dinv[s] * dinv[d];
}

// ---------------- fp32 tiled GEMM: C[M,BNcols] = A[M,K] @ B[K,BNcols] ----------------
// BM=64, BK=16, TM=4; BN/TN templated: (128,8) -> 256 thr, (64,4) -> 256 thr.
// B-fragment for TN=8 is split as cols {tx*4..+3} and {64+tx*4..+3} (2-way banks, free).

template <int BN, int TN>
__global__ __launch_bounds__(256) void gemm_kernel(
    const float* __restrict__ A, const float* __restrict__ B,
    float* __restrict__ C, int M, int K) {
    __shared__ float lds_a[16][68];    // [k][m], padded: stride 272B (16B-aligned, 2-way banks)
    __shared__ float lds_b[16][BN];    // [k][n]
    int tid = threadIdx.x;
    int bm = blockIdx.x * 64;
    int tx = tid & 15;
    int ty = tid >> 4;

    float acc[4][TN] = {};

    for (int k0 = 0; k0 < K; k0 += 16) {
        // A tile: 64 rows x 16 k, float4 along k, transpose into lds_a[k][m]
        {
            int r = tid >> 2;
            int kc = (tid & 3) << 2;
            int grow = bm + r;
            float4 av;
            if (grow < M) av = *(const float4*)(A + (size_t)grow * K + k0 + kc);
            else { av.x = av.y = av.z = av.w = 0.f; }
            lds_a[kc + 0][r] = av.x;
            lds_a[kc + 1][r] = av.y;
            lds_a[kc + 2][r] = av.z;
            lds_a[kc + 3][r] = av.w;
        }
        // B tile: 16 k x BN n; each thread writes BN*16/(4*256) float4s
        {
            const int nf4 = BN * 16 / 4;          // float4s in tile (512 or 256)
            int slot = tid;
            float4 bv = *(const float4*)(B + (size_t)(slot / (BN / 4)) * BN
                                           + (size_t)k0 * BN + (slot % (BN / 4)) * 4);
            // note: B rows are contiguous BN floats; linear float4 index works:
            *((float4*)&lds_b[0][0] + slot) = bv;
            if (nf4 > 256) {
                int slot2 = tid + 256;
                float4 bv2 = *((const float4*)(B + (size_t)k0 * BN) + slot2);
                *((float4*)&lds_b[0][0] + slot2) = bv2;
            }
        }
        __syncthreads();
#pragma unroll
        for (int k = 0; k < 16; k++) {
            float4 a4 = *(const float4*)&lds_a[k][ty << 2];
            float av[4] = {a4.x, a4.y, a4.z, a4.w};
            float bv[TN];
            float4 b4 = *(const float4*)&lds_b[k][tx << 2];
            bv[0] = b4.x; bv[1] = b4.y; bv[2] = b4.z; bv[3] = b4.w;
            if (TN == 8) {
                float4 b42 = *(const float4*)&lds_b[k][64 + (tx << 2)];
                bv[4] = b42.x; bv[5] = b42.y; bv[6] = b42.z; bv[7] = b42.w;
            }
#pragma unroll
            for (int i = 0; i < 4; i++)
#pragma unroll
                for (int j = 0; j < TN; j++)
                    acc[i][j] += av[i] * bv[j];
        }
        __syncthreads();
    }
#pragma unroll
    for (int i = 0; i < 4; i++) {
        int grow = bm + (ty << 2) + i;
        if (grow < M) {
            float4 o0;
            o0.x = acc[i][0]; o0.y = acc[i][1]; o0.z = acc[i][2]; o0.w = acc[i][3];
            *(float4*)(C + (size_t)grow * BN + (tx << 2)) = o0;
            if (TN == 8) {
                float4 o1;
                o1.x = acc[i][4]; o1.y = acc[i][5]; o1.z = acc[i][6]; o1.w = acc[i][7];
                *(float4*)(C + (size_t)grow * BN + 64 + (tx << 2)) = o1;
            }
        }
    }
}

// ---------------- aggregation: out[i] = act( sum_e w_e * t[src_e] + dinv[i]^2 * t[i] + b ) ----
// One wave per node; lane = feature pair (F=128) or feature (F=64).
// Inner loop: fixed-16 unrolled chunks, invalid lanes padded with w=0,j=0 so all
// 16 gathers per chunk are independent and in flight together.

template <int F, bool DOGELU>
__global__ __launch_bounds__(256) void agg_kernel(
    const float* __restrict__ t, const int* __restrict__ rowptr,
    const int* __restrict__ adj_src, const float* __restrict__ adj_w,
    const float* __restrict__ dinv, const float* __restrict__ bias,
    float* __restrict__ outp, int n) {
    int node = (int)((blockIdx.x * blockDim.x + threadIdx.x) >> 6);
    int lane = threadIdx.x & 63;
    if (node >= n) return;   // wave-uniform exit

    float wself = dinv[node];
    wself *= wself;
    int beg = rowptr[node];
    int end = rowptr[node + 1];

    if (F == 128) {
        const float2* t2 = (const float2*)t;
        float2 v = t2[(size_t)node * 64 + lane];
        float accx = wself * v.x, accy = wself * v.y;
        for (int e0 = beg; e0 < end; e0 += 64) {
            int rem = end - e0;
            int j = 0; float w = 0.f;
            if (lane < rem) { j = adj_src[e0 + lane]; w = adj_w[e0 + lane]; }
            int cnt = rem < 64 ? rem : 64;
            for (int c = 0; c < cnt; c += 16) {
#pragma unroll
                for (int i = 0; i < 16; i++) {
                    int jj = __builtin_amdgcn_readlane(j, c + i);
                    float ww = __int_as_float(
                        __builtin_amdgcn_readlane(__float_as_int(w), c + i));
                    float2 u = t2[(size_t)jj * 64 + lane];
                    accx += ww * u.x;
                    accy += ww * u.y;
                }
            }
        }
        float2 b = ((const float2*)bias)[lane];
        accx += b.x; accy += b.y;
        if (DOGELU) { accx = gelu_exact(accx); accy = gelu_exact(accy); }
        float2 o; o.x = accx; o.y = accy;
        ((float2*)outp)[(size_t)node * 64 + lane] = o;
    } else {  // F == 64
        float acc = wself * t[(size_t)node * 64 + lane];
        for (int e0 = beg; e0 < end; e0 += 64) {
            int rem = end - e0;
            int j = 0; float w = 0.f;
            if (lane < rem) { j = adj_src[e0 + lane]; w = adj_w[e0 + lane]; }
            int cnt = rem < 64 ? rem : 64;
            for (int c = 0; c < cnt; c += 16) {
#pragma unroll
                for (int i = 0; i < 16; i++) {
                    int jj = __builtin_amdgcn_readlane(j, c + i);
                    float ww = __int_as_float(
                        __builtin_amdgcn_readlane(__float_as_int(w), c + i));
                    acc += ww * t[(size_t)jj * 64 + lane];
                }
            }
        }
        acc += bias[lane];
        if (DOGELU) acc = gelu_exact(acc);
        outp[(size_t)node * 64 + lane] = acc;
    }
}

// ---------------- launch ----------------

extern "C" void kernel_launch(void* const* d_in, const int* in_sizes, int n_in,
                              void* d_out, int out_size, void* d_ws, size_t ws_size,
                              hipStream_t stream) {
    const float* x  = (const float*)d_in[0];
    const int* edge = (const int*)d_in[1];
    const float* W1 = (const float*)d_in[2];
    const float* b1 = (const float*)d_in[3];
    const float* W2 = (const float*)d_in[4];
    const float* b2 = (const float*)d_in[5];
    const float* W3 = (const float*)d_in[6];
    const float* b3 = (const float*)d_in[7];
    float* out = (float*)d_out;

    const int N = in_sizes[0] / NDIN;       // 50000
    const int E = in_sizes[1] / 2;          // 800000
    const int* src = edge;
    const int* dst = edge + E;
    const int NB = (N + 255) / 256;         // scan segments (196)

    // workspace carve-out (256B aligned)
    char* p = (char*)d_ws;
    auto alloc = [&](size_t bytes) {
        char* q = p;
        p += (bytes + 255) & ~(size_t)255;
        return q;
    };
    int*   count    = (int*)alloc((size_t)N * 4);
    int*   rowptr   = (int*)alloc((size_t)(N + 1) * 4);
    int*   blocksum = (int*)alloc((size_t)NB * 4);
    int*   blockoff = (int*)alloc((size_t)NB * 4);
    float* dinv     = (float*)alloc((size_t)N * 4);
    int*   adj_src  = (int*)alloc((size_t)E * 4);
    float* adj_w    = (float*)alloc((size_t)E * 4);
    float* tbuf     = (float*)alloc((size_t)N * NHID * 4);
    float* hbuf     = (float*)alloc((size_t)N * NHID * 4);

    hipMemsetAsync(count, 0, (size_t)N * 4, stream);

    // graph preprocessing
    count_kernel<<<(E + 255) / 256, 256, 0, stream>>>(dst, count, E);
    reduce_blocks_kernel<<<NB, 256, 0, stream>>>(count, blocksum, N);
    scan_partials_kernel<<<1, 256, 0, stream>>>(blocksum, blockoff, rowptr, NB, N);
    scan_blocks_kernel<<<NB, 256, 0, stream>>>(count, blockoff, rowptr, dinv, N);
    fill_kernel<<<(E + 255) / 256, 256, 0, stream>>>(src, dst, dinv, rowptr, count,
                                                     adj_src, adj_w, E);

    dim3 blk(256);
    int mtiles = (N + 63) / 64;             // 782
    int agg_blocks = (N + 3) / 4;           // 4 waves (nodes) per 256-thread block

    // layer 1
    gemm_kernel<128, 8><<<mtiles, blk, 0, stream>>>(x, W1, tbuf, N, NDIN);
    agg_kernel<128, true><<<agg_blocks, blk, 0, stream>>>(tbuf, rowptr, adj_src, adj_w,
                                                          dinv, b1, hbuf, N);
    // layer 2
    gemm_kernel<128, 8><<<mtiles, blk, 0, stream>>>(hbuf, W2, tbuf, N, NHID);
    agg_kernel<128, true><<<agg_blocks, blk, 0, stream>>>(tbuf, rowptr, adj_src, adj_w,
                                                          dinv, b2, hbuf, N);
    // layer 3 (no gelu)
    gemm_kernel<64, 4><<<mtiles, blk, 0, stream>>>(hbuf, W3, tbuf, N, NHID);
    agg_kernel<64, false><<<agg_blocks, blk, 0, stream>>>(tbuf, rowptr, adj_src, adj_w,
                                                          dinv, b3, out, N);
}

// Round 3
// 323.856 us; speedup vs baseline: 1.5346x; 1.1889x over previous
//
#include <hip/hip_runtime.h>
#include <math.h>

#define NDIN 128
#define NHID 128
#define NDOUT 64

typedef _Float16 half2_t __attribute__((ext_vector_type(2)));
typedef _Float16 half4_t __attribute__((ext_vector_type(4)));

__device__ __forceinline__ float gelu_exact(float x) {
    return 0.5f * x * (1.0f + erff(x * 0.70710678118654752f));
}

// ---------------- preprocessing ----------------

__global__ void count_kernel(const int* __restrict__ dst, int* __restrict__ count, int E) {
    int e = blockIdx.x * blockDim.x + threadIdx.x;
    if (e < E) atomicAdd(&count[dst[e]], 1);
}

// phase A: per-block (256-elem segment) reduction of count
__global__ __launch_bounds__(256) void reduce_blocks_kernel(
    const int* __restrict__ count, int* __restrict__ blocksum, int n) {
    __shared__ int s[256];
    int i = blockIdx.x * 256 + threadIdx.x;
    s[threadIdx.x] = (i < n) ? count[i] : 0;
    __syncthreads();
    for (int off = 128; off > 0; off >>= 1) {
        if (threadIdx.x < off) s[threadIdx.x] += s[threadIdx.x + off];
        __syncthreads();
    }
    if (threadIdx.x == 0) blocksum[blockIdx.x] = s[0];
}

// phase B: single-block scan over block partial sums (nb <= 256); writes rowptr[n]=total
__global__ __launch_bounds__(256) void scan_partials_kernel(
    const int* __restrict__ blocksum, int* __restrict__ blockoff,
    int* __restrict__ rowptr, int nb, int n) {
    __shared__ int s[256];
    int t = threadIdx.x;
    int v = (t < nb) ? blocksum[t] : 0;
    s[t] = v;
    __syncthreads();
    for (int off = 1; off < 256; off <<= 1) {
        int u = (t >= off) ? s[t - off] : 0;
        __syncthreads();
        s[t] += u;
        __syncthreads();
    }
    if (t < nb) blockoff[t] = s[t] - v;   // exclusive
    if (t == 255) rowptr[n] = s[255];     // grand total
}

// phase C: per-block scan of the 256-elem segment + add block offset; also emits dinv
__global__ __launch_bounds__(256) void scan_blocks_kernel(
    const int* __restrict__ count, const int* __restrict__ blockoff,
    int* __restrict__ rowptr, float* __restrict__ dinv, int n) {
    __shared__ int s[256];
    int i = blockIdx.x * 256 + threadIdx.x;
    int v = (i < n) ? count[i] : 0;
    s[threadIdx.x] = v;
    __syncthreads();
    for (int off = 1; off < 256; off <<= 1) {
        int u = (threadIdx.x >= off) ? s[threadIdx.x - off] : 0;
        __syncthreads();
        s[threadIdx.x] += u;
        __syncthreads();
    }
    if (i < n) {
        rowptr[i] = blockoff[blockIdx.x] + s[threadIdx.x] - v;  // exclusive
        dinv[i] = rsqrtf((float)(v + 1));                       // +1 self-loop
    }
}

// fill CSR; consumes count[] as a countdown cursor (atomicSub); adj = {src, w} interleaved
__global__ void fill_kernel(const int* __restrict__ src, const int* __restrict__ dst,
                            const float* __restrict__ dinv, const int* __restrict__ rowptr,
                            int* __restrict__ count, int2* __restrict__ adj, int E) {
    int e = blockIdx.x * blockDim.x + threadIdx.x;
    if (e >= E) return;
    int s = src[e], d = dst[e];
    int slot = atomicSub(&count[d], 1) - 1;   // deg-1 .. 0
    int p = rowptr[d] + slot;
    adj[p] = make_int2(s, __float_as_int(dinv[s] * dinv[d]));
}

// ---------------- fp32 tiled GEMM -> fp16 out: T[M,BN] = A[M,K] @ B[K,BN] ----------------
// BM=64, BK=16, TM=4; (BN,TN) = (128,8) or (64,4); 256 threads.

template <int BN, int TN>
__global__ __launch_bounds__(256) void gemm_kernel(
    const float* __restrict__ A, const float* __restrict__ B,
    _Float16* __restrict__ T, int M, int K) {
    __shared__ float lds_a[16][68];    // [k][m], padded (2-way banks = free)
    __shared__ float lds_b[16][BN];    // [k][n]
    int tid = threadIdx.x;
    int bm = blockIdx.x * 64;
    int tx = tid & 15;
    int ty = tid >> 4;

    float acc[4][TN] = {};

    for (int k0 = 0; k0 < K; k0 += 16) {
        // A tile: 64 rows x 16 k, float4 along k, transpose into lds_a[k][m]
        {
            int r = tid >> 2;
            int kc = (tid & 3) << 2;
            int grow = bm + r;
            float4 av;
            if (grow < M) av = *(const float4*)(A + (size_t)grow * K + k0 + kc);
            else { av.x = av.y = av.z = av.w = 0.f; }
            lds_a[kc + 0][r] = av.x;
            lds_a[kc + 1][r] = av.y;
            lds_a[kc + 2][r] = av.z;
            lds_a[kc + 3][r] = av.w;
        }
        // B tile: 16 k x BN n; linear float4 copy
        {
            const int nf4 = BN * 16 / 4;
            float4 bv = *((const float4*)(B + (size_t)k0 * BN) + tid);
            *((float4*)&lds_b[0][0] + tid) = bv;
            if (nf4 > 256) {
                float4 bv2 = *((const float4*)(B + (size_t)k0 * BN) + tid + 256);
                *((float4*)&lds_b[0][0] + tid + 256) = bv2;
            }
        }
        __syncthreads();
#pragma unroll
        for (int k = 0; k < 16; k++) {
            float4 a4 = *(const float4*)&lds_a[k][ty << 2];
            float av[4] = {a4.x, a4.y, a4.z, a4.w};
            float bv[TN];
            float4 b4 = *(const float4*)&lds_b[k][tx << 2];
            bv[0] = b4.x; bv[1] = b4.y; bv[2] = b4.z; bv[3] = b4.w;
            if (TN == 8) {
                float4 b42 = *(const float4*)&lds_b[k][64 + (tx << 2)];
                bv[4] = b42.x; bv[5] = b42.y; bv[6] = b42.z; bv[7] = b42.w;
            }
#pragma unroll
            for (int i = 0; i < 4; i++)
#pragma unroll
                for (int j = 0; j < TN; j++)
                    acc[i][j] += av[i] * bv[j];
        }
        __syncthreads();
    }
#pragma unroll
    for (int i = 0; i < 4; i++) {
        int grow = bm + (ty << 2) + i;
        if (grow < M) {
            half4_t o0;
            o0[0] = (_Float16)acc[i][0]; o0[1] = (_Float16)acc[i][1];
            o0[2] = (_Float16)acc[i][2]; o0[3] = (_Float16)acc[i][3];
            *(half4_t*)(T + (size_t)grow * BN + (tx << 2)) = o0;
            if (TN == 8) {
                half4_t o1;
                o1[0] = (_Float16)acc[i][4]; o1[1] = (_Float16)acc[i][5];
                o1[2] = (_Float16)acc[i][6]; o1[3] = (_Float16)acc[i][7];
                *(half4_t*)(T + (size_t)grow * BN + 64 + (tx << 2)) = o1;
            }
        }
    }
}

// ---------------- aggregation: out[i] = act( sum_e w_e * t[src_e] + dinv[i]^2 * t[i] + b ) ----
// One wave per node; t is fp16 (gather source), accumulate fp32.
// F=128: half2 per lane (4 B). F=64: one half per lane (2 B).

template <int F, bool DOGELU>
__global__ __launch_bounds__(256) void agg_kernel(
    const _Float16* __restrict__ t, const int* __restrict__ rowptr,
    const int2* __restrict__ adj, const float* __restrict__ dinv,
    const float* __restrict__ bias, float* __restrict__ outp, int n) {
    int node = (int)((blockIdx.x * blockDim.x + threadIdx.x) >> 6);
    int lane = threadIdx.x & 63;
    if (node >= n) return;   // wave-uniform exit

    float wself = dinv[node];
    wself *= wself;
    int beg = rowptr[node];
    int end = rowptr[node + 1];

    if (F == 128) {
        const half2_t* t2 = (const half2_t*)t;
        half2_t v = t2[(size_t)node * 64 + lane];
        float accx = wself * (float)v[0], accy = wself * (float)v[1];
        for (int e0 = beg; e0 < end; e0 += 64) {
            int rem = end - e0;
            int j = 0; float w = 0.f;
            if (lane < rem) {
                int2 ed = adj[e0 + lane];
                j = ed.x; w = __int_as_float(ed.y);
            }
            int cnt = rem < 64 ? rem : 64;
            for (int c = 0; c < cnt; c += 16) {
#pragma unroll
                for (int i = 0; i < 16; i++) {
                    int jj = __builtin_amdgcn_readlane(j, c + i);
                    float ww = __int_as_float(
                        __builtin_amdgcn_readlane(__float_as_int(w), c + i));
                    half2_t u = t2[(size_t)jj * 64 + lane];
                    accx += ww * (float)u[0];
                    accy += ww * (float)u[1];
                }
            }
        }
        float2 b = ((const float2*)bias)[lane];
        accx += b.x; accy += b.y;
        if (DOGELU) { accx = gelu_exact(accx); accy = gelu_exact(accy); }
        float2 o; o.x = accx; o.y = accy;
        ((float2*)outp)[(size_t)node * 64 + lane] = o;
    } else {  // F == 64
        float acc = wself * (float)t[(size_t)node * 64 + lane];
        for (int e0 = beg; e0 < end; e0 += 64) {
            int rem = end - e0;
            int j = 0; float w = 0.f;
            if (lane < rem) {
                int2 ed = adj[e0 + lane];
                j = ed.x; w = __int_as_float(ed.y);
            }
            int cnt = rem < 64 ? rem : 64;
            for (int c = 0; c < cnt; c += 16) {
#pragma unroll
                for (int i = 0; i < 16; i++) {
                    int jj = __builtin_amdgcn_readlane(j, c + i);
                    float ww = __int_as_float(
                        __builtin_amdgcn_readlane(__float_as_int(w), c + i));
                    acc += ww * (float)t[(size_t)jj * 64 + lane];
                }
            }
        }
        acc += bias[lane];
        if (DOGELU) acc = gelu_exact(acc);
        outp[(size_t)node * 64 + lane] = acc;
    }
}

// ---------------- launch ----------------

extern "C" void kernel_launch(void* const* d_in, const int* in_sizes, int n_in,
                              void* d_out, int out_size, void* d_ws, size_t ws_size,
                              hipStream_t stream) {
    const float* x  = (const float*)d_in[0];
    const int* edge = (const int*)d_in[1];
    const float* W1 = (const float*)d_in[2];
    const float* b1 = (const float*)d_in[3];
    const float* W2 = (const float*)d_in[4];
    const float* b2 = (const float*)d_in[5];
    const float* W3 = (const float*)d_in[6];
    const float* b3 = (const float*)d_in[7];
    float* out = (float*)d_out;

    const int N = in_sizes[0] / NDIN;       // 50000
    const int E = in_sizes[1] / 2;          // 800000
    const int* src = edge;
    const int* dst = edge + E;
    const int NB = (N + 255) / 256;         // scan segments (196)

    // workspace carve-out (256B aligned)
    char* p = (char*)d_ws;
    auto alloc = [&](size_t bytes) {
        char* q = p;
        p += (bytes + 255) & ~(size_t)255;
        return q;
    };
    int*       count    = (int*)alloc((size_t)N * 4);
    int*       rowptr   = (int*)alloc((size_t)(N + 1) * 4);
    int*       blocksum = (int*)alloc((size_t)NB * 4);
    int*       blockoff = (int*)alloc((size_t)NB * 4);
    float*     dinv     = (float*)alloc((size_t)N * 4);
    int2*      adj      = (int2*)alloc((size_t)E * 8);
    _Float16*  tbuf     = (_Float16*)alloc((size_t)N * NHID * 2);
    float*     hbuf     = (float*)alloc((size_t)N * NHID * 4);

    hipMemsetAsync(count, 0, (size_t)N * 4, stream);

    // graph preprocessing
    count_kernel<<<(E + 255) / 256, 256, 0, stream>>>(dst, count, E);
    reduce_blocks_kernel<<<NB, 256, 0, stream>>>(count, blocksum, N);
    scan_partials_kernel<<<1, 256, 0, stream>>>(blocksum, blockoff, rowptr, NB, N);
    scan_blocks_kernel<<<NB, 256, 0, stream>>>(count, blockoff, rowptr, dinv, N);
    fill_kernel<<<(E + 255) / 256, 256, 0, stream>>>(src, dst, dinv, rowptr, count,
                                                     adj, E);

    dim3 blk(256);
    int mtiles = (N + 63) / 64;             // 782
    int agg_blocks = (N + 3) / 4;           // 4 waves (nodes) per 256-thread block

    // layer 1
    gemm_kernel<128, 8><<<mtiles, blk, 0, stream>>>(x, W1, tbuf, N, NDIN);
    agg_kernel<128, true><<<agg_blocks, blk, 0, stream>>>(tbuf, rowptr, adj,
                                                          dinv, b1, hbuf, N);
    // layer 2
    gemm_kernel<128, 8><<<mtiles, blk, 0, stream>>>(hbuf, W2, tbuf, N, NHID);
    agg_kernel<128, true><<<agg_blocks, blk, 0, stream>>>(tbuf, rowptr, adj,
                                                          dinv, b2, hbuf, N);
    // layer 3 (no gelu)
    gemm_kernel<64, 4><<<mtiles, blk, 0, stream>>>(hbuf, W3, tbuf, N, NHID);
    agg_kernel<64, false><<<agg_blocks, blk, 0, stream>>>(tbuf, rowptr, adj,
                                                          dinv, b3, out, N);
}

// Round 4
// 292.691 us; speedup vs baseline: 1.6981x; 1.1065x over previous
//
#include <hip/hip_runtime.h>
#include <math.h>

#define NDIN 128
#define NHID 128
#define NDOUT 64

typedef _Float16 half2_t __attribute__((ext_vector_type(2)));
typedef _Float16 half4_t __attribute__((ext_vector_type(4)));
typedef _Float16 half8_t __attribute__((ext_vector_type(8)));
typedef float    float4v __attribute__((ext_vector_type(4)));

__device__ __forceinline__ float gelu_exact(float x) {
    return 0.5f * x * (1.0f + erff(x * 0.70710678118654752f));
}

// ---------------- preprocessing ----------------

__global__ void count_kernel(const int* __restrict__ dst, int* __restrict__ count, int E) {
    int e = blockIdx.x * blockDim.x + threadIdx.x;
    if (e < E) atomicAdd(&count[dst[e]], 1);
}

__global__ __launch_bounds__(256) void reduce_blocks_kernel(
    const int* __restrict__ count, int* __restrict__ blocksum, int n) {
    __shared__ int s[256];
    int i = blockIdx.x * 256 + threadIdx.x;
    s[threadIdx.x] = (i < n) ? count[i] : 0;
    __syncthreads();
    for (int off = 128; off > 0; off >>= 1) {
        if (threadIdx.x < off) s[threadIdx.x] += s[threadIdx.x + off];
        __syncthreads();
    }
    if (threadIdx.x == 0) blocksum[blockIdx.x] = s[0];
}

__global__ __launch_bounds__(256) void scan_partials_kernel(
    const int* __restrict__ blocksum, int* __restrict__ blockoff,
    int* __restrict__ rowptr, int nb, int n) {
    __shared__ int s[256];
    int t = threadIdx.x;
    int v = (t < nb) ? blocksum[t] : 0;
    s[t] = v;
    __syncthreads();
    for (int off = 1; off < 256; off <<= 1) {
        int u = (t >= off) ? s[t - off] : 0;
        __syncthreads();
        s[t] += u;
        __syncthreads();
    }
    if (t < nb) blockoff[t] = s[t] - v;
    if (t == 255) rowptr[n] = s[255];
}

__global__ __launch_bounds__(256) void scan_blocks_kernel(
    const int* __restrict__ count, const int* __restrict__ blockoff,
    int* __restrict__ rowptr, float* __restrict__ dinv, int n) {
    __shared__ int s[256];
    int i = blockIdx.x * 256 + threadIdx.x;
    int v = (i < n) ? count[i] : 0;
    s[threadIdx.x] = v;
    __syncthreads();
    for (int off = 1; off < 256; off <<= 1) {
        int u = (threadIdx.x >= off) ? s[threadIdx.x - off] : 0;
        __syncthreads();
        s[threadIdx.x] += u;
        __syncthreads();
    }
    if (i < n) {
        rowptr[i] = blockoff[blockIdx.x] + s[threadIdx.x] - v;
        dinv[i] = rsqrtf((float)(v + 1));
    }
}

__global__ void fill_kernel(const int* __restrict__ src, const int* __restrict__ dst,
                            const float* __restrict__ dinv, const int* __restrict__ rowptr,
                            int* __restrict__ count, int2* __restrict__ adj, int E) {
    int e = blockIdx.x * blockDim.x + threadIdx.x;
    if (e >= E) return;
    int s = src[e], d = dst[e];
    int slot = atomicSub(&count[d], 1) - 1;
    int p = rowptr[d] + slot;
    adj[p] = make_int2(s, __float_as_int(dinv[s] * dinv[d]));
}

// W[K][N] fp32 -> Wt[N][K] fp16 (32x32 LDS tile transpose)
__global__ __launch_bounds__(256) void wtrans_kernel(
    const float* __restrict__ W, _Float16* __restrict__ Wt, int K, int N) {
    __shared__ float tile[32][33];
    int tx = threadIdx.x & 31, ty = threadIdx.x >> 5;   // ty 0..7
    for (int i = 0; i < 32; i += 8) {
        int k = blockIdx.y * 32 + ty + i, n = blockIdx.x * 32 + tx;
        tile[ty + i][tx] = (k < K && n < N) ? W[(size_t)k * N + n] : 0.f;
    }
    __syncthreads();
    for (int i = 0; i < 32; i += 8) {
        int n = blockIdx.x * 32 + ty + i, k = blockIdx.y * 32 + tx;
        if (n < N && k < K) Wt[(size_t)n * K + k] = (_Float16)tile[tx][ty + i];
    }
}

// ---------------- fp16 MFMA GEMM: T[M,BN] = A[M,128] @ Wt^T, output fp16 ----------------
// K fixed = 128; whole K-panel staged once in LDS (no K-loop, one barrier).
// 256 threads = 4 waves; wave w computes rows [bm+16w, bm+16w+16) x all BN cols.
// mfma_f32_16x16x32_f16: A-frag lane holds A[m=lane&15][quad*8+j]; B-frag holds
// B[quad*8+j][n=lane&15] = lds_bt[n][quad*8+j]; D[row=quad*4+r][col=lane&15].

template <int BN, bool AF16>
__global__ __launch_bounds__(256) void gemm_mfma(
    const void* __restrict__ Aptr, const _Float16* __restrict__ Bt,
    _Float16* __restrict__ T, int M) {
    __shared__ _Float16 lds_a[64][136];     // +8 pad: fragment rows land on distinct bank quads
    __shared__ _Float16 lds_bt[BN][136];
    const int K = 128;
    int tid = threadIdx.x;
    int bm = blockIdx.x * 64;
    int wave = tid >> 6, lane = tid & 63;
    int m = lane & 15, quad = lane >> 4;

    // stage A (64 rows x 128 halves)
    if (AF16) {
        const _Float16* A = (const _Float16*)Aptr;
#pragma unroll
        for (int j = 0; j < 4; j++) {
            int c = tid + j * 256;              // 16B chunk id, 1024 total
            int r = c >> 4, col = (c & 15) << 3;
            int grow = bm + r;
            uint4 v = make_uint4(0, 0, 0, 0);
            if (grow < M) v = *(const uint4*)(A + (size_t)grow * K + col);
            *(uint4*)&lds_a[r][col] = v;
        }
    } else {
        const float* A = (const float*)Aptr;
#pragma unroll
        for (int j = 0; j < 8; j++) {
            int c = tid + j * 256;              // float4 id, 2048 total
            int r = c >> 5, col = (c & 31) << 2;
            int grow = bm + r;
            float4 v = make_float4(0.f, 0.f, 0.f, 0.f);
            if (grow < M) v = *(const float4*)(A + (size_t)grow * K + col);
            half4_t h;
            h[0] = (_Float16)v.x; h[1] = (_Float16)v.y;
            h[2] = (_Float16)v.z; h[3] = (_Float16)v.w;
            *(half4_t*)&lds_a[r][col] = h;
        }
    }
    // stage Bt (BN rows x 128 halves), linear coalesced copy
    {
        const int chunks = BN * K / 8;
        for (int c = tid; c < chunks; c += 256) {
            int r = c >> 4, col = (c & 15) << 3;
            *(uint4*)&lds_bt[r][col] = *(const uint4*)(Bt + (size_t)r * K + col);
        }
    }
    __syncthreads();

    const int NT = BN / 16;
    float4v acc[NT];
#pragma unroll
    for (int nt = 0; nt < NT; nt++) acc[nt] = (float4v){0.f, 0.f, 0.f, 0.f};

    int arow = (wave << 4) + m;
#pragma unroll
    for (int kc = 0; kc < K; kc += 32) {
        half8_t a = *(const half8_t*)&lds_a[arow][kc + quad * 8];
#pragma unroll
        for (int nt = 0; nt < NT; nt++) {
            half8_t b = *(const half8_t*)&lds_bt[nt * 16 + m][kc + quad * 8];
            acc[nt] = __builtin_amdgcn_mfma_f32_16x16x32_f16(a, b, acc[nt], 0, 0, 0);
        }
    }
    // epilogue: fp16 out
#pragma unroll
    for (int nt = 0; nt < NT; nt++) {
#pragma unroll
        for (int r = 0; r < 4; r++) {
            int grow = bm + (wave << 4) + (quad << 2) + r;
            if (grow < M) T[(size_t)grow * BN + nt * 16 + m] = (_Float16)acc[nt][r];
        }
    }
}

// ---------------- aggregation ----------------
// out[i] = act( sum_e w_e * t[src_e] + dinv[i]^2 * t[i] + b ); t fp16, accum fp32.
// OUTF16: write fp16 (feeds next MFMA GEMM); else fp32 (final output).

template <int F, bool DOGELU, bool OUTF16>
__global__ __launch_bounds__(256) void agg_kernel(
    const _Float16* __restrict__ t, const int* __restrict__ rowptr,
    const int2* __restrict__ adj, const float* __restrict__ dinv,
    const float* __restrict__ bias, void* __restrict__ outp, int n) {
    int node = (int)((blockIdx.x * blockDim.x + threadIdx.x) >> 6);
    int lane = threadIdx.x & 63;
    if (node >= n) return;   // wave-uniform exit

    float wself = dinv[node];
    wself *= wself;
    int beg = rowptr[node];
    int end = rowptr[node + 1];

    if (F == 128) {
        const half2_t* t2 = (const half2_t*)t;
        half2_t v = t2[(size_t)node * 64 + lane];
        float accx = wself * (float)v[0], accy = wself * (float)v[1];
        for (int e0 = beg; e0 < end; e0 += 64) {
            int rem = end - e0;
            int j = 0; float w = 0.f;
            if (lane < rem) {
                int2 ed = adj[e0 + lane];
                j = ed.x; w = __int_as_float(ed.y);
            }
            int cnt = rem < 64 ? rem : 64;
            for (int c = 0; c < cnt; c += 16) {
#pragma unroll
                for (int i = 0; i < 16; i++) {
                    int jj = __builtin_amdgcn_readlane(j, c + i);
                    float ww = __int_as_float(
                        __builtin_amdgcn_readlane(__float_as_int(w), c + i));
                    half2_t u = t2[(size_t)jj * 64 + lane];
                    accx += ww * (float)u[0];
                    accy += ww * (float)u[1];
                }
            }
        }
        float2 b = ((const float2*)bias)[lane];
        accx += b.x; accy += b.y;
        if (DOGELU) { accx = gelu_exact(accx); accy = gelu_exact(accy); }
        if (OUTF16) {
            half2_t o; o[0] = (_Float16)accx; o[1] = (_Float16)accy;
            ((half2_t*)outp)[(size_t)node * 64 + lane] = o;
        } else {
            float2 o; o.x = accx; o.y = accy;
            ((float2*)outp)[(size_t)node * 64 + lane] = o;
        }
    } else {  // F == 64
        float acc = wself * (float)t[(size_t)node * 64 + lane];
        for (int e0 = beg; e0 < end; e0 += 64) {
            int rem = end - e0;
            int j = 0; float w = 0.f;
            if (lane < rem) {
                int2 ed = adj[e0 + lane];
                j = ed.x; w = __int_as_float(ed.y);
            }
            int cnt = rem < 64 ? rem : 64;
            for (int c = 0; c < cnt; c += 16) {
#pragma unroll
                for (int i = 0; i < 16; i++) {
                    int jj = __builtin_amdgcn_readlane(j, c + i);
                    float ww = __int_as_float(
                        __builtin_amdgcn_readlane(__float_as_int(w), c + i));
                    acc += ww * (float)t[(size_t)jj * 64 + lane];
                }
            }
        }
        acc += bias[lane];
        if (DOGELU) acc = gelu_exact(acc);
        if (OUTF16) ((_Float16*)outp)[(size_t)node * 64 + lane] = (_Float16)acc;
        else        ((float*)outp)[(size_t)node * 64 + lane] = acc;
    }
}

// ---------------- launch ----------------

extern "C" void kernel_launch(void* const* d_in, const int* in_sizes, int n_in,
                              void* d_out, int out_size, void* d_ws, size_t ws_size,
                              hipStream_t stream) {
    const float* x  = (const float*)d_in[0];
    const int* edge = (const int*)d_in[1];
    const float* W1 = (const float*)d_in[2];
    const float* b1 = (const float*)d_in[3];
    const float* W2 = (const float*)d_in[4];
    const float* b2 = (const float*)d_in[5];
    const float* W3 = (const float*)d_in[6];
    const float* b3 = (const float*)d_in[7];
    float* out = (float*)d_out;

    const int N = in_sizes[0] / NDIN;       // 50000
    const int E = in_sizes[1] / 2;          // 800000
    const int* src = edge;
    const int* dst = edge + E;
    const int NB = (N + 255) / 256;

    // workspace carve-out (256B aligned)
    char* p = (char*)d_ws;
    auto alloc = [&](size_t bytes) {
        char* q = p;
        p += (bytes + 255) & ~(size_t)255;
        return q;
    };
    int*       count    = (int*)alloc((size_t)N * 4);
    int*       rowptr   = (int*)alloc((size_t)(N + 1) * 4);
    int*       blocksum = (int*)alloc((size_t)NB * 4);
    int*       blockoff = (int*)alloc((size_t)NB * 4);
    float*     dinv     = (float*)alloc((size_t)N * 4);
    int2*      adj      = (int2*)alloc((size_t)E * 8);
    _Float16*  W1t      = (_Float16*)alloc((size_t)NHID * NDIN * 2);
    _Float16*  W2t      = (_Float16*)alloc((size_t)NHID * NHID * 2);
    _Float16*  W3t      = (_Float16*)alloc((size_t)NDOUT * NHID * 2);
    _Float16*  tbuf     = (_Float16*)alloc((size_t)N * NHID * 2);
    _Float16*  hbuf     = (_Float16*)alloc((size_t)N * NHID * 2);

    hipMemsetAsync(count, 0, (size_t)N * 4, stream);

    // graph preprocessing
    count_kernel<<<(E + 255) / 256, 256, 0, stream>>>(dst, count, E);
    reduce_blocks_kernel<<<NB, 256, 0, stream>>>(count, blocksum, N);
    scan_partials_kernel<<<1, 256, 0, stream>>>(blocksum, blockoff, rowptr, NB, N);
    scan_blocks_kernel<<<NB, 256, 0, stream>>>(count, blockoff, rowptr, dinv, N);
    fill_kernel<<<(E + 255) / 256, 256, 0, stream>>>(src, dst, dinv, rowptr, count,
                                                     adj, E);
    // weight transpose+cast (64 KB each; once per call)
    wtrans_kernel<<<dim3(NHID / 32, NDIN / 32), 256, 0, stream>>>(W1, W1t, NDIN, NHID);
    wtrans_kernel<<<dim3(NHID / 32, NHID / 32), 256, 0, stream>>>(W2, W2t, NHID, NHID);
    wtrans_kernel<<<dim3(NDOUT / 32, NHID / 32), 256, 0, stream>>>(W3, W3t, NHID, NDOUT);

    dim3 blk(256);
    int mtiles = (N + 63) / 64;             // 782
    int agg_blocks = (N + 3) / 4;

    // layer 1
    gemm_mfma<128, false><<<mtiles, blk, 0, stream>>>(x, W1t, tbuf, N);
    agg_kernel<128, true, true><<<agg_blocks, blk, 0, stream>>>(tbuf, rowptr, adj,
                                                                dinv, b1, hbuf, N);
    // layer 2
    gemm_mfma<128, true><<<mtiles, blk, 0, stream>>>(hbuf, W2t, tbuf, N);
    agg_kernel<128, true, true><<<agg_blocks, blk, 0, stream>>>(tbuf, rowptr, adj,
                                                                dinv, b2, hbuf, N);
    // layer 3 (no gelu, fp32 out)
    gemm_mfma<64, true><<<mtiles, blk, 0, stream>>>(hbuf, W3t, tbuf, N);
    agg_kernel<64, false, false><<<agg_blocks, blk, 0, stream>>>(tbuf, rowptr, adj,
                                                                 dinv, b3, out, N);
}